// Round 2
// baseline (212.395 us; speedup 1.0000x reference)
//
#include <hip/hip_runtime.h>
#include <stdint.h>

#define AS1q __attribute__((address_space(1)))
#define AS3q __attribute__((address_space(3)))

typedef unsigned short US;
typedef __bf16 bf16x8 __attribute__((ext_vector_type(8)));
typedef float f32x4 __attribute__((ext_vector_type(4)));
typedef float f32x16 __attribute__((ext_vector_type(16)));
typedef float f32x2 __attribute__((ext_vector_type(2)));
typedef __bf16 bf16x2 __attribute__((ext_vector_type(2)));

#define LOG2E 1.44269504088896340736f

__device__ __forceinline__ US f2bf(float f) {
  union { float f; uint32_t u; } c; c.f = f;
  uint32_t u = c.u;
  return (US)((u + 0x7fffu + ((u >> 16) & 1u)) >> 16);
}

__device__ __forceinline__ bf16x8 asb(uint4 u) {
  union { uint4 u; bf16x8 b; } c; c.u = u; return c.b;
}

__device__ __forceinline__ uint32_t pk2(float a, float b) {
  f32x2 fv; fv[0] = a; fv[1] = b;
  bf16x2 bb = __builtin_convertvector(fv, bf16x2);
  union { bf16x2 b; uint32_t u; } c; c.b = bb; return c.u;
}

__device__ __forceinline__ void gload16(const void* g, void* l) {
  __builtin_amdgcn_global_load_lds((AS1q void*)(void*)g, (AS3q void*)l, 16, 0, 0);
}

// raw barrier: no implicit vmcnt(0) drain (unlike __syncthreads) — required for
// the counted-vmcnt deep pipeline. memory-clobber fences stop compiler motion.
__device__ __forceinline__ void bar() {
  asm volatile("" ::: "memory");
  __builtin_amdgcn_s_barrier();
  asm volatile("" ::: "memory");
}

#define VM8 asm volatile("s_waitcnt vmcnt(8)" ::: "memory")

// ------------- prep: fused q/k/v fp32->bf16 + 4 weight transposes -------------
__global__ void prep_kernel(const float* __restrict__ q, const float* __restrict__ k,
                            const float* __restrict__ v,
                            const float* __restrict__ w0, const float* __restrict__ w1,
                            const float* __restrict__ w2, const float* __restrict__ w3,
                            US* __restrict__ qb, US* __restrict__ kb, US* __restrict__ vb,
                            US* __restrict__ t0, US* __restrict__ t1,
                            US* __restrict__ t2, US* __restrict__ t3) {
  __shared__ US T[64 * 68];
  const int bx = blockIdx.x;
  const int t = threadIdx.x;
  if (bx < 6144) {
    const int ten = bx >> 11, chunk = bx & 2047;
    const float* s; US* d;
    if (ten == 0)      { s = q; d = qb; }
    else if (ten == 1) { s = k; d = kb; }
    else               { s = v; d = vb; }
    int i = (chunk * 256 + t) * 8;
    float4 f0 = *(const float4*)&s[i];
    float4 f1 = *(const float4*)&s[i + 4];
    ushort4 u0, u1;
    u0.x = f2bf(f0.x); u0.y = f2bf(f0.y); u0.z = f2bf(f0.z); u0.w = f2bf(f0.w);
    u1.x = f2bf(f1.x); u1.y = f2bf(f1.y); u1.z = f2bf(f1.z); u1.w = f2bf(f1.w);
    *(ushort4*)&d[i] = u0;
    *(ushort4*)&d[i + 4] = u1;
    return;
  }
  const int idx = bx - 6144;
  const int wsel = idx >> 8, rem = idx & 255;
  const int n0 = (rem & 15) * 64, k0 = (rem >> 4) * 64;
  const float* W; US* Wt;
  if (wsel == 0)      { W = w0; Wt = t0; }
  else if (wsel == 1) { W = w1; Wt = t1; }
  else if (wsel == 2) { W = w2; Wt = t2; }
  else                { W = w3; Wt = t3; }
#pragma unroll
  for (int it = 0; it < 4; ++it) {
    int p = t + it * 256;
    int row = p >> 4, c4 = (p & 15) * 4;
    float4 f = *(const float4*)&W[(k0 + row) * 1024 + n0 + c4];
    ushort4 u;
    u.x = f2bf(f.x); u.y = f2bf(f.y); u.z = f2bf(f.z); u.w = f2bf(f.w);
    *(ushort4*)&T[row * 68 + c4] = u;
  }
  __syncthreads();
#pragma unroll
  for (int it = 0; it < 4; ++it) {
    int p = t + it * 256;
    int rn = p >> 4, ck = (p & 15) * 4;
    ushort4 o;
    o.x = T[(ck + 0) * 68 + rn];
    o.y = T[(ck + 1) * 68 + rn];
    o.z = T[(ck + 2) * 68 + rn];
    o.w = T[(ck + 3) * 68 + rn];
    *(ushort4*)&Wt[(n0 + rn) * 1024 + k0 + ck] = o;
  }
}

// ---------------- QKV projection: 256x256 tile, BK=64, 8-phase counted-vmcnt ----------
// 512 thr = 8 waves (2M x 4N). LDS: A/B each [2 slots][256][64] bf16, XOR-swizzled
// chunks (chunk ^= row&7) staged via pre-swizzled GLOBAL source + linear LDS dest.
// B-frags -> regs once per K-tile (phase 0), A-frags per quadrant phase.
// Stage schedule (per iter i computing tiles T=2i [ph1-4, slot0], T+1 [ph5-8, slot1]):
//  ph1: A-s1 P1,P3 <- T+1 | ph2: B-s0 P0,P1 <- T+2 | ph3: A-s0 P0,P2 <- T+2
//  ph4: B-s0 P2,P3 <- T+2 | ph5: A-s0 P1,P3 <- T+2 | ph6: B-s1 P0,P1 <- T+3
//  ph7: A-s1 P0,P2 <- T+3 | ph8: B-s1 P2,P3 <- T+3
// vmcnt(8) at end of ph2/4/6/8 — every stage->read pair verified covered; never drains.
#define STA(t, P) gload16(gA + (size_t)(P) * 65536 + (t) * 64, lA + ((t) & 1) * 16384 + (P) * 4096)
#define STB(t, P) gload16(gB + (size_t)(P) * 65536 + (t) * 64, lB + ((t) & 1) * 16384 + (P) * 4096)

#define MM(d, a, b) d = __builtin_amdgcn_mfma_f32_16x16x32_bf16(asb(a), asb(b), d, 0, 0, 0)

#define PHASE(MF0, STAGE_CODE, VMW)                                                      \
  {                                                                                      \
    uint4 ar0[2], ar1[2];                                                                \
    {                                                                                    \
      const int row0 = arowb + (MF0) * 16;                                               \
      const int row1 = arowb + (MF0) * 16 + 16;                                          \
      ar0[0] = *(const uint4*)&Ab[row0 * 64 + (((0 + quad) ^ (row0 & 7)) << 3)];         \
      ar0[1] = *(const uint4*)&Ab[row0 * 64 + (((4 + quad) ^ (row0 & 7)) << 3)];         \
      ar1[0] = *(const uint4*)&Ab[row1 * 64 + (((0 + quad) ^ (row1 & 7)) << 3)];         \
      ar1[1] = *(const uint4*)&Ab[row1 * 64 + (((4 + quad) ^ (row1 & 7)) << 3)];         \
    }                                                                                    \
    STAGE_CODE;                                                                          \
    bar();                                                                               \
    __builtin_amdgcn_s_setprio(1);                                                       \
    _Pragma("unroll") for (int nf = 0; nf < 4; ++nf) {                                   \
      if constexpr (SWAP) {                                                              \
        MM(acc[MF0][nf], br[nf][0], ar0[0]);                                             \
        MM(acc[MF0][nf], br[nf][1], ar0[1]);                                             \
        MM(acc[(MF0) + 1][nf], br[nf][0], ar1[0]);                                       \
        MM(acc[(MF0) + 1][nf], br[nf][1], ar1[1]);                                       \
      } else {                                                                           \
        MM(acc[MF0][nf], ar0[0], br[nf][0]);                                             \
        MM(acc[MF0][nf], ar0[1], br[nf][1]);                                             \
        MM(acc[(MF0) + 1][nf], ar1[0], br[nf][0]);                                       \
        MM(acc[(MF0) + 1][nf], ar1[1], br[nf][1]);                                       \
      }                                                                                  \
    }                                                                                    \
    __builtin_amdgcn_s_setprio(0);                                                       \
    VMW;                                                                                 \
    bar();                                                                               \
  }

template <bool SWAP>
__device__ __forceinline__ void qkv8_core(const US* __restrict__ A, const US* __restrict__ Bw,
                                          int m0, US* Al, US* Bl, f32x4 acc[8][4]) {
  const int tid = threadIdx.x;
  const int wave = tid >> 6, lane = tid & 63;
  const int quad = lane >> 4, l16 = lane & 15;
  const int wm2 = wave >> 2, wn4 = wave & 3;
#pragma unroll
  for (int i = 0; i < 8; ++i)
#pragma unroll
    for (int j = 0; j < 4; ++j) acc[i][j] = (f32x4)0.0f;

  // staging addressing: thread t writes 16B at linear LDS (pass base + t*16B);
  // physical chunk t&7 of row t>>3 -> logical (global) chunk = (t&7) ^ (row&7).
  const int srow = tid >> 3;
  const int sch = (tid & 7) ^ (srow & 7);
  const US* gA = A + (size_t)(m0 + srow) * 1024 + sch * 8;
  const US* gB = Bw + (size_t)srow * 1024 + sch * 8;
  US* lA = Al + wave * 512;
  US* lB = Bl + wave * 512;

  // prologue: tile0 full (A,B), tile1 B full + A P0,P2 (P1,P3 staged in-loop ph1)
  STA(0, 0); STA(0, 1); STA(0, 2); STA(0, 3);
  STB(0, 0); STB(0, 1); STB(0, 2); STB(0, 3);
  STB(1, 0); STB(1, 1); STB(1, 2); STB(1, 3);
  STA(1, 0); STA(1, 2);
  asm volatile("s_waitcnt vmcnt(6)" ::: "memory");
  bar();

  const int arowb = wm2 * 128 + l16;
  const int browb = wn4 * 64 + l16;

  for (int i = 0; i < 8; ++i) {
    const int ti1 = 2 * i + 1, ti2 = 2 * i + 2, ti3 = 2 * i + 3;
    const bool more = (i < 7);
    // ---- window 0: tile 2i (slot 0), phases 1-4 ----
    {
      const US* Ab = Al;
      const US* Bb = Bl;
      uint4 br[4][2];
#pragma unroll
      for (int nf = 0; nf < 4; ++nf) {
        const int row = browb + nf * 16;
        br[nf][0] = *(const uint4*)&Bb[row * 64 + (((0 + quad) ^ (row & 7)) << 3)];
        br[nf][1] = *(const uint4*)&Bb[row * 64 + (((4 + quad) ^ (row & 7)) << 3)];
      }
      PHASE(0, { STA(ti1, 1); STA(ti1, 3); }, )
      PHASE(2, { if (more) { STB(ti2, 0); STB(ti2, 1); } }, VM8)
      PHASE(4, { if (more) { STA(ti2, 0); STA(ti2, 2); } }, )
      PHASE(6, { if (more) { STB(ti2, 2); STB(ti2, 3); } }, VM8)
    }
    // ---- window 1: tile 2i+1 (slot 1), phases 5-8 ----
    {
      const US* Ab = Al + 16384;
      const US* Bb = Bl + 16384;
      uint4 br[4][2];
#pragma unroll
      for (int nf = 0; nf < 4; ++nf) {
        const int row = browb + nf * 16;
        br[nf][0] = *(const uint4*)&Bb[row * 64 + (((0 + quad) ^ (row & 7)) << 3)];
        br[nf][1] = *(const uint4*)&Bb[row * 64 + (((4 + quad) ^ (row & 7)) << 3)];
      }
      PHASE(0, { if (more) { STA(ti2, 1); STA(ti2, 3); } }, )
      PHASE(2, { if (more) { STB(ti3, 0); STB(ti3, 1); } }, VM8)
      PHASE(4, { if (more) { STA(ti3, 0); STA(ti3, 2); } }, )
      PHASE(6, { if (more) { STB(ti3, 2); STB(ti3, 3); } }, VM8)
    }
  }
}

__global__ __launch_bounds__(512, 2) void gemm_qkv_kernel(
    const US* __restrict__ qb, const US* __restrict__ kb, const US* __restrict__ vb,
    const US* __restrict__ wfT,
    const float* __restrict__ bq, const float* __restrict__ bk, const float* __restrict__ bv,
    US* __restrict__ qh, US* __restrict__ kh, US* __restrict__ vt) {
  __shared__ __align__(16) US Al[2 * 16384], Bl[2 * 16384];  // 64KB + 64KB
  const int m0 = blockIdx.x * 256;
  const int nb = blockIdx.y;                // 0..11
  const int which = nb >> 2;                // 0=Q 1=K 2=V
  const int n0loc = (nb & 3) * 256;         // n offset within tensor's 1024
  const US* A = (which == 0) ? qb : (which == 1) ? kb : vb;
  const float* bias = (which == 0) ? bq : (which == 1) ? bk : bv;
  const US* Bw = wfT + ((size_t)which * 1024 + n0loc) * 1024;

  const int tid = threadIdx.x;
  const int wave = tid >> 6, lane = tid & 63;
  const int quad = lane >> 4, l16 = lane & 15;
  const int wm2 = wave >> 2, wn4 = wave & 3;

  f32x4 acc[8][4];
  if (which == 2) {
    qkv8_core<true>(A, Bw, m0, Al, Bl, acc);
    // SWAP: C tile transposed — rows = n(d), cols = m(token=l16)
#pragma unroll
    for (int nf = 0; nf < 4; ++nf) {
#pragma unroll
      for (int r = 0; r < 4; ++r) {
        const int dg = n0loc + wn4 * 64 + nf * 16 + quad * 4 + r;
        const float bval = bias[dg];
        const int hh = dg >> 6, dd = dg & 63;
#pragma unroll
        for (int mf = 0; mf < 8; ++mf) {
          const int m = m0 + wm2 * 128 + mf * 16 + l16;
          const int bb = m >> 11, ss = m & 2047;
          vt[(((size_t)bb * 16 + hh) * 64 + dd) * 2048 + ss] = f2bf(acc[mf][nf][r] + bval);
        }
      }
    }
  } else {
    qkv8_core<false>(A, Bw, m0, Al, Bl, acc);
    US* O = (which == 0) ? qh : kh;
    const float scale = (which == 0) ? LOG2E : 1.0f;
#pragma unroll
    for (int nf = 0; nf < 4; ++nf) {
      const int nl = n0loc + wn4 * 64 + nf * 16 + l16;
      const float bval = bias[nl];
      const int hh = nl >> 6, d = nl & 63;
#pragma unroll
      for (int mf = 0; mf < 8; ++mf) {
#pragma unroll
        for (int r = 0; r < 4; ++r) {
          const int m = m0 + wm2 * 128 + mf * 16 + quad * 4 + r;
          const int bb = m >> 11, ss = m & 2047;
          O[(((size_t)bb * 16 + hh) * 2048 + ss) * 64 + d] = f2bf((acc[mf][nf][r] + bval) * scale);
        }
      }
    }
  }
}

// Output projection: ao bf16 [4096][1024] @ woT + bo -> fp32 out
__global__ __launch_bounds__(256, 4) void gemm_out_kernel(
    const US* __restrict__ ao, const US* __restrict__ woT,
    const float* __restrict__ bo, float* __restrict__ out) {
  __shared__ __align__(16) US As[4096], Bs[2048];
  const int m0 = blockIdx.x * 128, n0 = blockIdx.y * 64;
  const int tid = threadIdx.x;
  const int wave = tid >> 6, lane = tid & 63;
  const int quad = lane >> 4, l16 = lane & 15;
  f32x4 acc[2][4];
#pragma unroll
  for (int i = 0; i < 2; ++i)
#pragma unroll
    for (int j = 0; j < 4; ++j) acc[i][j] = (f32x4)0.0f;
  const int arow0 = tid >> 2, koff = (tid & 3) * 8;
  for (int k0 = 0; k0 < 1024; k0 += 32) {
    gload16(ao + (m0 + arow0) * 1024 + k0 + koff, As + wave * 512);
    gload16(ao + (m0 + arow0 + 64) * 1024 + k0 + koff, As + 2048 + wave * 512);
    gload16(woT + (n0 + arow0) * 1024 + k0 + koff, Bs + wave * 512);
    __syncthreads();
    uint4 af[2], bf_[4];
#pragma unroll
    for (int mt = 0; mt < 2; ++mt)
      af[mt] = *(const uint4*)&As[(wave * 32 + mt * 16 + l16) * 32 + quad * 8];
#pragma unroll
    for (int nt = 0; nt < 4; ++nt)
      bf_[nt] = *(const uint4*)&Bs[(nt * 16 + l16) * 32 + quad * 8];
#pragma unroll
    for (int mt = 0; mt < 2; ++mt)
#pragma unroll
      for (int nt = 0; nt < 4; ++nt)
        acc[mt][nt] = __builtin_amdgcn_mfma_f32_16x16x32_bf16(asb(af[mt]), asb(bf_[nt]),
                                                              acc[mt][nt], 0, 0, 0);
    __syncthreads();
  }
#pragma unroll
  for (int nt = 0; nt < 4; ++nt) {
    int n = n0 + nt * 16 + l16;
    float bval = bo[n];
#pragma unroll
    for (int mt = 0; mt < 2; ++mt) {
#pragma unroll
      for (int r = 0; r < 4; ++r) {
        int m = m0 + wave * 32 + mt * 16 + quad * 4 + r;
        out[m * 1024 + n] = acc[mt][nt][r] + bval;
      }
    }
  }
}

// ------------- causal attention: 512 thr (8 waves), S^T/O^T form, 128 keys/iter ------
__global__ __launch_bounds__(512, 2) void attn_kernel(
    const US* __restrict__ qh, const US* __restrict__ kh,
    const US* __restrict__ vt, US* __restrict__ aout) {
  __shared__ __align__(16) char arena[73728];
  US* KsA = (US*)arena;
  US* VsA = (US*)(arena + 32768);
  US* Qs  = (US*)(arena + 65536);
  float* Oex = (float*)arena;                  // [4][64][68]
  float* lEx = (float*)(arena + 69632);        // [4][64]

  const int tid = threadIdx.x;
  const int wave = tid >> 6, lane = tid & 63;
  const int l31 = lane & 31, lh = lane >> 5;
  const int w_m = wave & 1, w_k = wave >> 1;   // w_k in 0..3
  const int bh = blockIdx.x;
  const int b = bh >> 4, h = bh & 15;
  const int jg = blockIdx.y;

  const US* gkb = kh + (size_t)bh * 2048 * 64;
  const US* gvb = vt + (size_t)bh * 64 * 2048;

  for (int ei = 0; ei < 2; ++ei) {
    const int qt = ei ? jg : (31 - jg);
    const int q0 = qt * 64;
    const int nit = (qt >> 1) + 1;   // 128-key pair iterations
    __syncthreads();  // previous tile's epilogue reads / buffer reuse
    {
      const US* gq = qh + ((size_t)bh * 2048 + q0) * 64;
      {
        int p = tid;
        int row = p >> 3, c = (p & 7) ^ (row & 7);
        gload16(gq + row * 64 + c * 8, Qs + wave * 512);
      }
#pragma unroll
      for (int ro = 0; ro < 2; ++ro) {
        int p = tid + ro * 512;
        int row = p >> 3, c = (p & 7) ^ (row & 7);
        gload16(gkb + row * 64 + c * 8, KsA + ro * 4096 + wave * 512);
      }
#pragma unroll
      for (int ro = 0; ro < 2; ++ro) {
        int p = tid + ro * 512;
        int row = p >> 4, c = (p & 15) ^ (row & 15);
        gload16(gvb + row * 2048 + c * 8, VsA + ro * 4096 + wave * 512);
      }
    }
    __syncthreads();

    const int qrow = w_m * 32 + l31;
    uint4 bq[4];
#pragma unroll
    for (int s = 0; s < 4; ++s)
      bq[s] = *(const uint4*)&Qs[qrow * 64 + (((2 * s + lh) ^ (qrow & 7)) * 8)];
    const int q_g = q0 + qrow;

    float l_lane = 0.0f;
    f32x16 Oa0 = (f32x16)0.0f, Oa1 = (f32x16)0.0f;

    for (int it = 0; it < nit; ++it) {
      const int cb = it & 1;
      const int kb = it * 128;
      if (it) __syncthreads();
      if (it + 1 < nit) {
        const US* gk = gkb + (kb + 128) * 64;
        const US* gv = gvb + (kb + 128);
        US* kd = KsA + (cb ^ 1) * 8192;
        US* vd = VsA + (cb ^ 1) * 8192;
#pragma unroll
        for (int ro = 0; ro < 2; ++ro) {
          int p = tid + ro * 512;
          int row = p >> 3, c = (p & 7) ^ (row & 7);
          gload16(gk + row * 64 + c * 8, kd + ro * 4096 + wave * 512);
        }
#pragma unroll
        for (int ro = 0; ro < 2; ++ro) {
          int p = tid + ro * 512;
          int row = p >> 4, c = (p & 15) ^ (row & 15);
          gload16(gv + row * 2048 + c * 8, vd + ro * 4096 + wave * 512);
        }
      }
      const US* Kc = KsA + cb * 8192;
      const US* Vc = VsA + cb * 8192;

      f32x16 sa0 = (f32x16)0.0f;
      const int kr0 = w_k * 32 + l31;
#pragma unroll
      for (int s = 0; s < 4; ++s) {
        uint4 ka0 = *(const uint4*)&Kc[kr0 * 64 + (((2 * s + lh) ^ (kr0 & 7)) * 8)];
        sa0 = __builtin_amdgcn_mfma_f32_32x32x16_bf16(asb(ka0), asb(bq[s]), sa0, 0, 0, 0);
      }

      const bool diag = (it == nit - 1);
      float e[16];
      const int kbase = kb + w_k * 32 + 4 * lh;
#pragma unroll
      for (int r = 0; r < 16; ++r) {
        float ev = __builtin_amdgcn_exp2f(sa0[r]);
        if (diag) {
          int key_g = kbase + (r & 3) + 8 * (r >> 2);
          if (key_g > q_g) ev = 0.0f;
        }
        e[r] = ev;
        l_lane += ev;
      }

#pragma unroll
      for (int s2 = 0; s2 < 2; ++s2) {
        uint32_t PA0 = pk2(e[8 * s2 + 0], e[8 * s2 + 1]);
        uint32_t PA1 = pk2(e[8 * s2 + 2], e[8 * s2 + 3]);
        uint32_t PB0 = pk2(e[8 * s2 + 4], e[8 * s2 + 5]);
        uint32_t PB1 = pk2(e[8 * s2 + 6], e[8 * s2 + 7]);
        uint32_t XA0 = (uint32_t)__shfl_xor((int)PA0, 32, 64);
        uint32_t XA1 = (uint32_t)__shfl_xor((int)PA1, 32, 64);
        uint32_t XB0 = (uint32_t)__shfl_xor((int)PB0, 32, 64);
        uint32_t XB1 = (uint32_t)__shfl_xor((int)PB1, 32, 64);
        uint4 bp;
        bp.x = lh ? XB0 : PA0;
        bp.y = lh ? XB1 : PA1;
        bp.z = lh ? PB0 : XA0;
        bp.w = lh ? PB1 : XA1;
        const int c_log = w_k * 4 + s2 * 2 + lh;
        int vr0 = l31;
        uint4 va0 = *(const uint4*)&Vc[vr0 * 128 + ((c_log ^ (vr0 & 15)) * 8)];
        Oa0 = __builtin_amdgcn_mfma_f32_32x32x16_bf16(asb(va0), asb(bp), Oa0, 0, 0, 0);
        int vr1 = 32 + l31;
        uint4 va1 = *(const uint4*)&Vc[vr1 * 128 + ((c_log ^ (vr1 & 15)) * 8)];
        Oa1 = __builtin_amdgcn_mfma_f32_32x32x16_bf16(asb(va1), asb(bp), Oa1, 0, 0, 0);
      }
    }

    float l_q = l_lane + __shfl_xor(l_lane, 32, 64);

    __syncthreads();  // K/V buffers dead; overlay epilogue exchange
    {
      float* myO = Oex + w_k * (64 * 68);
      int q_idx = w_m * 32 + l31;
#pragma unroll
      for (int r = 0; r < 16; ++r) {
        int dr = 4 * lh + (r & 3) + 8 * (r >> 2);
        myO[q_idx * 68 + dr] = Oa0[r];
        myO[q_idx * 68 + 32 + dr] = Oa1[r];
      }
      if (lh == 0) lEx[w_k * 64 + q_idx] = l_q;
    }
    __syncthreads();
    {
      int q_idx = tid >> 3;
      int dseg = (tid & 7) * 8;
      float inv = 1.0f / (lEx[q_idx] + lEx[64 + q_idx] + lEx[128 + q_idx] + lEx[192 + q_idx]);
      union { US s[8]; uint4 v; } ob;
#pragma unroll
      for (int t2 = 0; t2 < 8; ++t2) {
        float o = Oex[q_idx * 68 + dseg + t2]
                + Oex[64 * 68 + q_idx * 68 + dseg + t2]
                + Oex[2 * 64 * 68 + q_idx * 68 + dseg + t2]
                + Oex[3 * 64 * 68 + q_idx * 68 + dseg + t2];
        ob.s[t2] = f2bf(o * inv);
      }
      US* dst = aout + ((size_t)b * 2048 + q0 + q_idx) * 1024 + h * 64 + dseg;
      *(uint4*)dst = ob.v;
    }
  }
}

extern "C" void kernel_launch(void* const* d_in, const int* in_sizes, int n_in,
                              void* d_out, int out_size, void* d_ws, size_t ws_size,
                              hipStream_t stream) {
  const float* q  = (const float*)d_in[0];
  const float* k  = (const float*)d_in[1];
  const float* v  = (const float*)d_in[2];
  const float* wq = (const float*)d_in[3];
  const float* bq = (const float*)d_in[4];
  const float* wk = (const float*)d_in[5];
  const float* bk = (const float*)d_in[6];
  const float* wv = (const float*)d_in[7];
  const float* bv = (const float*)d_in[8];
  const float* wo = (const float*)d_in[9];
  const float* bo = (const float*)d_in[10];
  float* out = (float*)d_out;

  char* ws = (char*)d_ws;
  const size_t MB = 1024 * 1024;
  US* qb  = (US*)(ws + 0 * MB);
  US* kb  = (US*)(ws + 8 * MB);
  US* vb  = (US*)(ws + 16 * MB);
  US* wqT = (US*)(ws + 24 * MB);  // wqT/wkT/wvT contiguous -> fused [3072][1024]
  US* wkT = (US*)(ws + 26 * MB);
  US* wvT = (US*)(ws + 28 * MB);
  US* woT = (US*)(ws + 30 * MB);
  US* qh  = (US*)(ws + 32 * MB);  // [B,H,S,D] (pre-scaled by log2e)
  US* kh  = (US*)(ws + 40 * MB);  // [B,H,S,D]
  US* vt  = (US*)(ws + 48 * MB);  // [B,H,D,S]
  US* ao  = (US*)(ws + 56 * MB);  // [B*S, 1024]

  prep_kernel<<<7168, 256, 0, stream>>>(q, k, v, wq, wk, wv, wo,
                                        qb, kb, vb, wqT, wkT, wvT, woT);
  gemm_qkv_kernel<<<dim3(16, 12), 512, 0, stream>>>(qb, kb, vb, wqT,
                                                    bq, bk, bv, qh, kh, vt);
  attn_kernel<<<dim3(32, 16), 512, 0, stream>>>(qh, kh, vt, ao);
  gemm_out_kernel<<<dim3(32, 16), 256, 0, stream>>>(ao, woT, bo, out);
}

// Round 4
// 201.036 us; speedup vs baseline: 1.0565x; 1.0565x over previous
//
#include <hip/hip_runtime.h>
#include <stdint.h>

#define AS1q __attribute__((address_space(1)))
#define AS3q __attribute__((address_space(3)))

typedef unsigned short US;
typedef __bf16 bf16x8 __attribute__((ext_vector_type(8)));
typedef float f32x4 __attribute__((ext_vector_type(4)));
typedef float f32x16 __attribute__((ext_vector_type(16)));
typedef float f32x2 __attribute__((ext_vector_type(2)));
typedef __bf16 bf16x2 __attribute__((ext_vector_type(2)));

#define LOG2E 1.44269504088896340736f

__device__ __forceinline__ US f2bf(float f) {
  union { float f; uint32_t u; } c; c.f = f;
  uint32_t u = c.u;
  return (US)((u + 0x7fffu + ((u >> 16) & 1u)) >> 16);
}

__device__ __forceinline__ bf16x8 asb(uint4 u) {
  union { uint4 u; bf16x8 b; } c; c.u = u; return c.b;
}

__device__ __forceinline__ uint32_t pk2(float a, float b) {
  f32x2 fv; fv[0] = a; fv[1] = b;
  bf16x2 bb = __builtin_convertvector(fv, bf16x2);
  union { bf16x2 b; uint32_t u; } c; c.b = bb; return c.u;
}

__device__ __forceinline__ void gload16(const void* g, void* l) {
  __builtin_amdgcn_global_load_lds((AS1q void*)(void*)g, (AS3q void*)l, 16, 0, 0);
}

// ------------- prep: fused q/k/v fp32->bf16 + 4 weight transposes -------------
__global__ void prep_kernel(const float* __restrict__ q, const float* __restrict__ k,
                            const float* __restrict__ v,
                            const float* __restrict__ w0, const float* __restrict__ w1,
                            const float* __restrict__ w2, const float* __restrict__ w3,
                            US* __restrict__ qb, US* __restrict__ kb, US* __restrict__ vb,
                            US* __restrict__ t0, US* __restrict__ t1,
                            US* __restrict__ t2, US* __restrict__ t3) {
  __shared__ US T[64 * 68];
  const int bx = blockIdx.x;
  const int t = threadIdx.x;
  if (bx < 6144) {
    const int ten = bx >> 11, chunk = bx & 2047;
    const float* s; US* d;
    if (ten == 0)      { s = q; d = qb; }
    else if (ten == 1) { s = k; d = kb; }
    else               { s = v; d = vb; }
    int i = (chunk * 256 + t) * 8;
    float4 f0 = *(const float4*)&s[i];
    float4 f1 = *(const float4*)&s[i + 4];
    ushort4 u0, u1;
    u0.x = f2bf(f0.x); u0.y = f2bf(f0.y); u0.z = f2bf(f0.z); u0.w = f2bf(f0.w);
    u1.x = f2bf(f1.x); u1.y = f2bf(f1.y); u1.z = f2bf(f1.z); u1.w = f2bf(f1.w);
    *(ushort4*)&d[i] = u0;
    *(ushort4*)&d[i + 4] = u1;
    return;
  }
  const int idx = bx - 6144;
  const int wsel = idx >> 8, rem = idx & 255;
  const int n0 = (rem & 15) * 64, k0 = (rem >> 4) * 64;
  const float* W; US* Wt;
  if (wsel == 0)      { W = w0; Wt = t0; }
  else if (wsel == 1) { W = w1; Wt = t1; }
  else if (wsel == 2) { W = w2; Wt = t2; }
  else                { W = w3; Wt = t3; }
#pragma unroll
  for (int it = 0; it < 4; ++it) {
    int p = t + it * 256;
    int row = p >> 4, c4 = (p & 15) * 4;
    float4 f = *(const float4*)&W[(k0 + row) * 1024 + n0 + c4];
    ushort4 u;
    u.x = f2bf(f.x); u.y = f2bf(f.y); u.z = f2bf(f.z); u.w = f2bf(f.w);
    *(ushort4*)&T[row * 68 + c4] = u;
  }
  __syncthreads();
#pragma unroll
  for (int it = 0; it < 4; ++it) {
    int p = t + it * 256;
    int rn = p >> 4, ck = (p & 15) * 4;
    ushort4 o;
    o.x = T[(ck + 0) * 68 + rn];
    o.y = T[(ck + 1) * 68 + rn];
    o.z = T[(ck + 2) * 68 + rn];
    o.w = T[(ck + 3) * 68 + rn];
    *(ushort4*)&Wt[(n0 + rn) * 1024 + k0 + ck] = o;
  }
}

// ------------- GEMM core: 128x128 tile, BK=64, XOR-swizzled LDS, 2-phase ------------
// Staging: pre-swizzled global source + linear global_load_lds dest (rule #21):
// thread t writes 16B at LDS elem t*8 -> row t>>3 (+32c), physical chunk t&7;
// global source chunk = (t&7) ^ (row&7), so logical chunk q of row r sits at
// physical chunk q^(r&7). Frag reads XOR the same way -> 0 bank conflicts (R2-proven).
// BK=64 halves the barrier-pairs + vmcnt(0) drains vs BK=32 (32 MFMA per pair).
template <bool SWAP>
__device__ __forceinline__ void gemm_core64(const US* A, const US* Wt,
                                            int m0, int n0, US* As, US* Bs,
                                            f32x4 acc[4][4]) {
  const int tid = threadIdx.x;
  const int wave = tid >> 6, lane = tid & 63;
  const int quad = lane >> 4, l16 = lane & 15;
  const int wm = wave >> 1, wn = wave & 1;
#pragma unroll
  for (int i = 0; i < 4; ++i)
#pragma unroll
    for (int j = 0; j < 4; ++j) acc[i][j] = (f32x4)0.0f;

  const int srow = tid >> 3;                 // 0..31
  const int sch = (tid & 7) ^ (srow & 7);    // pre-swizzled global chunk
  const US* gA = A + (size_t)(m0 + srow) * 1024 + sch * 8;
  const US* gB = Wt + (size_t)(n0 + srow) * 1024 + sch * 8;
  US* lA = As + wave * 512;
  US* lB = Bs + wave * 512;

  for (int k0 = 0; k0 < 1024; k0 += 64) {
#pragma unroll
    for (int c = 0; c < 4; ++c) {
      gload16(gA + (size_t)c * 32 * 1024 + k0, lA + c * 2048);
      gload16(gB + (size_t)c * 32 * 1024 + k0, lB + c * 2048);
    }
    __syncthreads();
    uint4 af[4][2], bf_[4][2];
#pragma unroll
    for (int mt = 0; mt < 4; ++mt) {
      const int row = wm * 64 + mt * 16 + l16;
      af[mt][0] = *(const uint4*)&As[row * 64 + ((quad ^ (row & 7)) << 3)];
      af[mt][1] = *(const uint4*)&As[row * 64 + (((4 + quad) ^ (row & 7)) << 3)];
    }
#pragma unroll
    for (int nt = 0; nt < 4; ++nt) {
      const int row = wn * 64 + nt * 16 + l16;
      bf_[nt][0] = *(const uint4*)&Bs[row * 64 + ((quad ^ (row & 7)) << 3)];
      bf_[nt][1] = *(const uint4*)&Bs[row * 64 + (((4 + quad) ^ (row & 7)) << 3)];
    }
#pragma unroll
    for (int i = 0; i < 4; ++i)
#pragma unroll
      for (int j = 0; j < 4; ++j) {
        if (SWAP) {
          acc[i][j] = __builtin_amdgcn_mfma_f32_16x16x32_bf16(asb(bf_[i][0]), asb(af[j][0]),
                                                              acc[i][j], 0, 0, 0);
          acc[i][j] = __builtin_amdgcn_mfma_f32_16x16x32_bf16(asb(bf_[i][1]), asb(af[j][1]),
                                                              acc[i][j], 0, 0, 0);
        } else {
          acc[i][j] = __builtin_amdgcn_mfma_f32_16x16x32_bf16(asb(af[i][0]), asb(bf_[j][0]),
                                                              acc[i][j], 0, 0, 0);
          acc[i][j] = __builtin_amdgcn_mfma_f32_16x16x32_bf16(asb(af[i][1]), asb(bf_[j][1]),
                                                              acc[i][j], 0, 0, 0);
        }
      }
    __syncthreads();
  }
}

// Fused QKV projection (N=3072). Q is scaled by log2(e) so attn can use raw exp2.
__global__ __launch_bounds__(256, 4) void gemm_qkv_kernel(
    const US* __restrict__ qb, const US* __restrict__ kb, const US* __restrict__ vb,
    const US* __restrict__ wfT,
    const float* __restrict__ bq, const float* __restrict__ bk, const float* __restrict__ bv,
    US* __restrict__ qh, US* __restrict__ kh, US* __restrict__ vt) {
  __shared__ __align__(16) US As[8192], Bs[8192];  // [128][64] each, 32 KB total
  const int m0 = blockIdx.x * 128, n0 = blockIdx.y * 128;
  const int which = n0 >> 10;
  const int nl0 = n0 & 1023;
  const US* A = (which == 0) ? qb : (which == 1) ? kb : vb;
  const float* bias = (which == 0) ? bq : (which == 1) ? bk : bv;
  const int tid = threadIdx.x, wave = tid >> 6, lane = tid & 63;
  const int quad = lane >> 4, l16 = lane & 15;
  const int wm = wave >> 1, wn = wave & 1;
  f32x4 acc[4][4];
  if (which == 2) {
    gemm_core64<true>(A, wfT, m0, n0, As, Bs, acc);
#pragma unroll
    for (int nt = 0; nt < 4; ++nt) {
      int dg = nl0 + wn * 64 + nt * 16 + quad * 4;
#pragma unroll
      for (int r = 0; r < 4; ++r) {
        int d = dg + r;
        float bval = bias[d];
        int hh = d >> 6, dd = d & 63;
#pragma unroll
        for (int mt = 0; mt < 4; ++mt) {
          int sg = m0 + wm * 64 + mt * 16;
          int bb = sg >> 11, ss = sg & 2047;
          vt[(((size_t)bb * 16 + hh) * 64 + dd) * 2048 + ss + l16] =
              f2bf(acc[nt][mt][r] + bval);
        }
      }
    }
  } else {
    gemm_core64<false>(A, wfT, m0, n0, As, Bs, acc);
    US* O = (which == 0) ? qh : kh;
    const float scale = (which == 0) ? LOG2E : 1.0f;
#pragma unroll
    for (int nt = 0; nt < 4; ++nt) {
      int nl = nl0 + wn * 64 + nt * 16 + l16;
      float bval = bias[nl];
      int hh = nl >> 6, d = nl & 63;
#pragma unroll
      for (int mt = 0; mt < 4; ++mt) {
#pragma unroll
        for (int r = 0; r < 4; ++r) {
          int m = m0 + wm * 64 + mt * 16 + quad * 4 + r;
          int bb = m >> 11, s = m & 2047;
          O[((bb * 16 + hh) * 2048 + s) * 64 + d] = f2bf((acc[mt][nt][r] + bval) * scale);
        }
      }
    }
  }
}

// Output projection: ao bf16 [4096][1024] @ woT + bo -> fp32 out. 128x64 tile, BK=64.
__global__ __launch_bounds__(256, 4) void gemm_out_kernel(
    const US* __restrict__ ao, const US* __restrict__ woT,
    const float* __restrict__ bo, float* __restrict__ out) {
  __shared__ __align__(16) US As[8192], Bs[4096];  // A [128][64], B [64][64]
  const int m0 = blockIdx.x * 128, n0 = blockIdx.y * 64;
  const int tid = threadIdx.x;
  const int wave = tid >> 6, lane = tid & 63;
  const int quad = lane >> 4, l16 = lane & 15;
  f32x4 acc[2][4];
#pragma unroll
  for (int i = 0; i < 2; ++i)
#pragma unroll
    for (int j = 0; j < 4; ++j) acc[i][j] = (f32x4)0.0f;

  const int srow = tid >> 3;
  const int sch = (tid & 7) ^ (srow & 7);
  const US* gA = ao + (size_t)(m0 + srow) * 1024 + sch * 8;
  const US* gB = woT + (size_t)(n0 + srow) * 1024 + sch * 8;
  US* lA = As + wave * 512;
  US* lB = Bs + wave * 512;

  for (int k0 = 0; k0 < 1024; k0 += 64) {
#pragma unroll
    for (int c = 0; c < 4; ++c)
      gload16(gA + (size_t)c * 32 * 1024 + k0, lA + c * 2048);
#pragma unroll
    for (int c = 0; c < 2; ++c)
      gload16(gB + (size_t)c * 32 * 1024 + k0, lB + c * 2048);
    __syncthreads();
    uint4 af[2][2], bf_[4][2];
#pragma unroll
    for (int mt = 0; mt < 2; ++mt) {
      const int row = wave * 32 + mt * 16 + l16;
      af[mt][0] = *(const uint4*)&As[row * 64 + ((quad ^ (row & 7)) << 3)];
      af[mt][1] = *(const uint4*)&As[row * 64 + (((4 + quad) ^ (row & 7)) << 3)];
    }
#pragma unroll
    for (int nt = 0; nt < 4; ++nt) {
      const int row = nt * 16 + l16;
      bf_[nt][0] = *(const uint4*)&Bs[row * 64 + ((quad ^ (row & 7)) << 3)];
      bf_[nt][1] = *(const uint4*)&Bs[row * 64 + (((4 + quad) ^ (row & 7)) << 3)];
    }
#pragma unroll
    for (int mt = 0; mt < 2; ++mt)
#pragma unroll
      for (int nt = 0; nt < 4; ++nt) {
        acc[mt][nt] = __builtin_amdgcn_mfma_f32_16x16x32_bf16(asb(af[mt][0]), asb(bf_[nt][0]),
                                                              acc[mt][nt], 0, 0, 0);
        acc[mt][nt] = __builtin_amdgcn_mfma_f32_16x16x32_bf16(asb(af[mt][1]), asb(bf_[nt][1]),
                                                              acc[mt][nt], 0, 0, 0);
      }
    __syncthreads();
  }
#pragma unroll
  for (int nt = 0; nt < 4; ++nt) {
    int n = n0 + nt * 16 + l16;
    float bval = bo[n];
#pragma unroll
    for (int mt = 0; mt < 2; ++mt) {
#pragma unroll
      for (int r = 0; r < 4; ++r) {
        int m = m0 + wave * 32 + mt * 16 + quad * 4 + r;
        out[m * 1024 + n] = acc[mt][nt][r] + bval;
      }
    }
  }
}

// ------------- causal attention: 512 thr (8 waves), S^T/O^T form, 128 keys/iter ------
__global__ __launch_bounds__(512, 2) void attn_kernel(
    const US* __restrict__ qh, const US* __restrict__ kh,
    const US* __restrict__ vt, US* __restrict__ aout) {
  __shared__ __align__(16) char arena[73728];
  US* KsA = (US*)arena;
  US* VsA = (US*)(arena + 32768);
  US* Qs  = (US*)(arena + 65536);
  float* Oex = (float*)arena;                  // [4][64][68]
  float* lEx = (float*)(arena + 69632);        // [4][64]

  const int tid = threadIdx.x;
  const int wave = tid >> 6, lane = tid & 63;
  const int l31 = lane & 31, lh = lane >> 5;
  const int w_m = wave & 1, w_k = wave >> 1;   // w_k in 0..3
  const int bh = blockIdx.x;
  const int b = bh >> 4, h = bh & 15;
  const int jg = blockIdx.y;

  const US* gkb = kh + (size_t)bh * 2048 * 64;
  const US* gvb = vt + (size_t)bh * 64 * 2048;

  for (int ei = 0; ei < 2; ++ei) {
    const int qt = ei ? jg : (31 - jg);
    const int q0 = qt * 64;
    const int nit = (qt >> 1) + 1;   // 128-key pair iterations
    __syncthreads();  // previous tile's epilogue reads / buffer reuse
    {
      const US* gq = qh + ((size_t)bh * 2048 + q0) * 64;
      {
        int p = tid;
        int row = p >> 3, c = (p & 7) ^ (row & 7);
        gload16(gq + row * 64 + c * 8, Qs + wave * 512);
      }
#pragma unroll
      for (int ro = 0; ro < 2; ++ro) {
        int p = tid + ro * 512;
        int row = p >> 3, c = (p & 7) ^ (row & 7);
        gload16(gkb + row * 64 + c * 8, KsA + ro * 4096 + wave * 512);
      }
#pragma unroll
      for (int ro = 0; ro < 2; ++ro) {
        int p = tid + ro * 512;
        int row = p >> 4, c = (p & 15) ^ (row & 15);
        gload16(gvb + row * 2048 + c * 8, VsA + ro * 4096 + wave * 512);
      }
    }
    __syncthreads();

    const int qrow = w_m * 32 + l31;
    uint4 bq[4];
#pragma unroll
    for (int s = 0; s < 4; ++s)
      bq[s] = *(const uint4*)&Qs[qrow * 64 + (((2 * s + lh) ^ (qrow & 7)) * 8)];
    const int q_g = q0 + qrow;

    float l_lane = 0.0f;
    f32x16 Oa0 = (f32x16)0.0f, Oa1 = (f32x16)0.0f;

    for (int it = 0; it < nit; ++it) {
      const int cb = it & 1;
      const int kb = it * 128;
      if (it) __syncthreads();
      if (it + 1 < nit) {
        const US* gk = gkb + (kb + 128) * 64;
        const US* gv = gvb + (kb + 128);
        US* kd = KsA + (cb ^ 1) * 8192;
        US* vd = VsA + (cb ^ 1) * 8192;
#pragma unroll
        for (int ro = 0; ro < 2; ++ro) {
          int p = tid + ro * 512;
          int row = p >> 3, c = (p & 7) ^ (row & 7);
          gload16(gk + row * 64 + c * 8, kd + ro * 4096 + wave * 512);
        }
#pragma unroll
        for (int ro = 0; ro < 2; ++ro) {
          int p = tid + ro * 512;
          int row = p >> 4, c = (p & 15) ^ (row & 15);
          gload16(gv + row * 2048 + c * 8, vd + ro * 4096 + wave * 512);
        }
      }
      const US* Kc = KsA + cb * 8192;
      const US* Vc = VsA + cb * 8192;

      f32x16 sa0 = (f32x16)0.0f;
      const int kr0 = w_k * 32 + l31;
#pragma unroll
      for (int s = 0; s < 4; ++s) {
        uint4 ka0 = *(const uint4*)&Kc[kr0 * 64 + (((2 * s + lh) ^ (kr0 & 7)) * 8)];
        sa0 = __builtin_amdgcn_mfma_f32_32x32x16_bf16(asb(ka0), asb(bq[s]), sa0, 0, 0, 0);
      }

      const bool diag = (it == nit - 1);
      float e[16];
      const int kbase = kb + w_k * 32 + 4 * lh;
#pragma unroll
      for (int r = 0; r < 16; ++r) {
        float ev = __builtin_amdgcn_exp2f(sa0[r]);
        if (diag) {
          int key_g = kbase + (r & 3) + 8 * (r >> 2);
          if (key_g > q_g) ev = 0.0f;
        }
        e[r] = ev;
        l_lane += ev;
      }

      // P^T B-frags via half-wave exchange (2 shuffles per s2: each lane only needs
      // the cross-half words of ONE operand pair, so pre-select lh?PA:PB then swap).
#pragma unroll
      for (int s2 = 0; s2 < 2; ++s2) {
        uint32_t PA0 = pk2(e[8 * s2 + 0], e[8 * s2 + 1]);
        uint32_t PA1 = pk2(e[8 * s2 + 2], e[8 * s2 + 3]);
        uint32_t PB0 = pk2(e[8 * s2 + 4], e[8 * s2 + 5]);
        uint32_t PB1 = pk2(e[8 * s2 + 6], e[8 * s2 + 7]);
        uint32_t W0 = (uint32_t)__shfl_xor((int)(lh ? PA0 : PB0), 32, 64);
        uint32_t W1 = (uint32_t)__shfl_xor((int)(lh ? PA1 : PB1), 32, 64);
        uint4 bp;
        bp.x = lh ? W0 : PA0;
        bp.y = lh ? W1 : PA1;
        bp.z = lh ? PB0 : W0;
        bp.w = lh ? PB1 : W1;
        const int c_log = w_k * 4 + s2 * 2 + lh;
        int vr0 = l31;
        uint4 va0 = *(const uint4*)&Vc[vr0 * 128 + ((c_log ^ (vr0 & 15)) * 8)];
        Oa0 = __builtin_amdgcn_mfma_f32_32x32x16_bf16(asb(va0), asb(bp), Oa0, 0, 0, 0);
        int vr1 = 32 + l31;
        uint4 va1 = *(const uint4*)&Vc[vr1 * 128 + ((c_log ^ (vr1 & 15)) * 8)];
        Oa1 = __builtin_amdgcn_mfma_f32_32x32x16_bf16(asb(va1), asb(bp), Oa1, 0, 0, 0);
      }
    }

    float l_q = l_lane + __shfl_xor(l_lane, 32, 64);

    __syncthreads();  // K/V buffers dead; overlay epilogue exchange
    {
      float* myO = Oex + w_k * (64 * 68);
      int q_idx = w_m * 32 + l31;
#pragma unroll
      for (int r = 0; r < 16; ++r) {
        int dr = 4 * lh + (r & 3) + 8 * (r >> 2);
        myO[q_idx * 68 + dr] = Oa0[r];
        myO[q_idx * 68 + 32 + dr] = Oa1[r];
      }
      if (lh == 0) lEx[w_k * 64 + q_idx] = l_q;
    }
    __syncthreads();
    {
      int q_idx = tid >> 3;
      int dseg = (tid & 7) * 8;
      float inv = 1.0f / (lEx[q_idx] + lEx[64 + q_idx] + lEx[128 + q_idx] + lEx[192 + q_idx]);
      union { US s[8]; uint4 v; } ob;
#pragma unroll
      for (int t2 = 0; t2 < 8; ++t2) {
        float o = Oex[q_idx * 68 + dseg + t2]
                + Oex[64 * 68 + q_idx * 68 + dseg + t2]
                + Oex[2 * 64 * 68 + q_idx * 68 + dseg + t2]
                + Oex[3 * 64 * 68 + q_idx * 68 + dseg + t2];
        ob.s[t2] = f2bf(o * inv);
      }
      US* dst = aout + ((size_t)b * 2048 + q0 + q_idx) * 1024 + h * 64 + dseg;
      *(uint4*)dst = ob.v;
    }
  }
}

extern "C" void kernel_launch(void* const* d_in, const int* in_sizes, int n_in,
                              void* d_out, int out_size, void* d_ws, size_t ws_size,
                              hipStream_t stream) {
  const float* q  = (const float*)d_in[0];
  const float* k  = (const float*)d_in[1];
  const float* v  = (const float*)d_in[2];
  const float* wq = (const float*)d_in[3];
  const float* bq = (const float*)d_in[4];
  const float* wk = (const float*)d_in[5];
  const float* bk = (const float*)d_in[6];
  const float* wv = (const float*)d_in[7];
  const float* bv = (const float*)d_in[8];
  const float* wo = (const float*)d_in[9];
  const float* bo = (const float*)d_in[10];
  float* out = (float*)d_out;

  char* ws = (char*)d_ws;
  const size_t MB = 1024 * 1024;
  US* qb  = (US*)(ws + 0 * MB);
  US* kb  = (US*)(ws + 8 * MB);
  US* vb  = (US*)(ws + 16 * MB);
  US* wqT = (US*)(ws + 24 * MB);  // wqT/wkT/wvT contiguous -> fused [3072][1024]
  US* wkT = (US*)(ws + 26 * MB);
  US* wvT = (US*)(ws + 28 * MB);
  US* woT = (US*)(ws + 30 * MB);
  US* qh  = (US*)(ws + 32 * MB);  // [B,H,S,D] (pre-scaled by log2e)
  US* kh  = (US*)(ws + 40 * MB);  // [B,H,S,D]
  US* vt  = (US*)(ws + 48 * MB);  // [B,H,D,S]
  US* ao  = (US*)(ws + 56 * MB);  // [B*S, 1024]

  prep_kernel<<<7168, 256, 0, stream>>>(q, k, v, wq, wk, wv, wo,
                                        qb, kb, vb, wqT, wkT, wvT, woT);
  gemm_qkv_kernel<<<dim3(32, 24), 256, 0, stream>>>(qb, kb, vb, wqT,
                                                    bq, bk, bv, qh, kh, vt);
  attn_kernel<<<dim3(32, 16), 512, 0, stream>>>(qh, kh, vt, ao);
  gemm_out_kernel<<<dim3(32, 16), 256, 0, stream>>>(ao, woT, bo, out);
}